// Round 5
// baseline (197.037 us; speedup 1.0000x reference)
//
#include <hip/hip_runtime.h>

// Problem constants
#define INC    256
#define HIN    56
#define WIN    56
#define HOUT   19
#define WOUT   58
#define HW     3136          // HIN*WIN

typedef short frag8 __attribute__((ext_vector_type(8)));   // 8 bf16 bits (4 VGPRs)
typedef float f32x4 __attribute__((ext_vector_type(4)));   // MFMA accumulator

static __device__ __forceinline__ unsigned short f2bf(float f) {
    unsigned u = __float_as_uint(f);
    u += 0x7fffu + ((u >> 16) & 1u);      // round-to-nearest-even
    return (unsigned short)(u >> 16);
}

// f32 pair -> packed 2x bf16 (RNE), lo16 = a, hi16 = b
static __device__ __forceinline__ unsigned cvtpk(float a, float b) {
    unsigned r;
    asm("v_cvt_pk_bf16_f32 %0, %1, %2" : "=v"(r) : "v"(a), "v"(b));
    return r;
}

#define VMCNT(n) asm volatile("s_waitcnt vmcnt(" #n ")" ::: "memory")
#define LGKM0()  asm volatile("s_waitcnt lgkmcnt(0)" ::: "memory")
#define FENCE()  asm volatile("" ::: "memory")
#define SB0()    __builtin_amdgcn_sched_barrier(0)

// ---------------------------------------------------------------------------
// prep_weff: unchanged (R8 chunk-major layout).
//   Asw[ks2 12][o_tile 16][ksl 2][lane 64][j 8] bf16, ks2 = ks>>1, ksl = ks&1
// ---------------------------------------------------------------------------
__global__ __launch_bounds__(256) void prep_weff(
    const float* __restrict__ lego,    // [64][64][3]
    const float* __restrict__ coefs,   // [4][256][64]
    const float* __restrict__ comb,    // [4][256][64]
    unsigned short* __restrict__ Asw)
{
    __shared__ int   idxS[4];
    __shared__ float cofS[4];
    const int t  = threadIdx.x;
    const int kx = blockIdx.x;         // 0..2
    const int o  = blockIdx.y;         // 0..255
    const int wv = t >> 6, l = t & 63;

    float v  = comb[(wv * 256 + o) * 64 + l];
    int   bi = l;
    #pragma unroll
    for (int off = 32; off >= 1; off >>= 1) {
        float ov = __shfl_xor(v, off, 64);
        int   oi = __shfl_xor(bi, off, 64);
        if (ov > v || (ov == v && oi < bi)) { v = ov; bi = oi; }
    }
    if (l == 0) {
        idxS[wv] = bi;
        cofS[wv] = coefs[(wv * 256 + o) * 64 + bi];
    }
    __syncthreads();

    const int k  = kx * 256 + t;       // 0..767
    const int kh = k >> 8, c = k & 255;
    const int i  = c >> 6, cl = c & 63;
    float w = cofS[i] * lego[idxS[i] * 192 + cl * 3 + kh];

    const int o_tile = o >> 4, m = o & 15;
    const int ks = k >> 5, kc = (k >> 3) & 3, j = k & 7;
    const int ks2 = ks >> 1, ksl = ks & 1;
    Asw[((((size_t)ks2 * 16 + o_tile) * 2 + ksl) * 64 + kc * 16 + m) * 8 + j] = f2bf(w);
}

// ---------------------------------------------------------------------------
// R9 conv. R4/R6/R8 all plateaued at ~74us despite different staging; shared
// cost was the B-assembly path: 64 ds_read_b32 + 32 cvtpk per wave per chunk
// (f32 in LDS, every wave redundantly converting). R9 converts ONCE at stage
// time in registers and stores bf16 FRAGMENT-LINEAR, so compute reads are
// 8 ds_read_b128 per wave per chunk (R4-proven conflict-free pattern), while
// keeping R8's proven pipeline discipline (sched_barrier-pinned issue order,
// counted VMCNT, one raw s_barrier per chunk).
//
// Per-thread staging: 16 coalesced dword loads (8 channels x 2 cols, cols
// cw and cw+32) -> 8 cvtpk -> 2 ds_write_b128 into buf[(q+1)&1].
// Pipeline (steady iter q):  [in flight: A(q) in regs, L(q+1) 16 loads]
//   compute(q)  (8 ds_read_b128 + 32 MFMA; compiler auto-waits A(q) w/
//               vmcnt(16), keeping L(q+1))
//   SB0; LOADA(q+1) (8 dwordx4); SB0
//   VMCNT(8)    -> retires L(q+1), keeps A(q+1)
//   W(q+1): cvt+2x ds_write; LOADL(q+2) reuses L regs (WAR via cvt use)
//   SB0; lgkmcnt(0); s_barrier
// Buffer safety w/ 1 barrier/iter: W(q+1) hits buf[(q+1)&1], last read in
// compute(q-1) which precedes iter q-1's barrier; barrier precedes W(q+1).
// h==0 (row<0, chunks 0..3): loads always issued (rc=0) and zeroed by *zmask
// -> vmcnt counts uniform; correct even if compiler branches (VMCNT(N) with
// fewer outstanding is a no-op and zero-fill needs no wait).
// Col 56..63 fragments: slot from unclamped col (every slot written once,
// finite garbage), value from clamped col 55; feed only discarded outputs.
// Registers ~ acc64 + A32 + L16 + voff16 + misc ~= 155 <= 170 ((256,3) cap).
// LDS 16 KB. 3 blocks/CU (VGPR-capped), 12 waves/CU.
// ---------------------------------------------------------------------------
__global__ __launch_bounds__(256, 3) void conv_mfma(
    const float* __restrict__ x,             // [32][256][56][56]
    const unsigned short* __restrict__ Asw,  // [12][16][2][64][8]
    float* __restrict__ out)                 // [32][256][19][58]
{
    __shared__ unsigned short Xs[2][4096];   // 2 x 8 KB bf16, fragment-linear

    const int t  = threadIdx.x;
    const int h  = blockIdx.x;               // 0..18
    const int b  = blockIdx.y;               // 0..31
    const int l  = t & 63;
    const int lo = l & 15;
    const int hi = l >> 4;                   // = kc for A/B fragment lanes
    const int wv = t >> 6;

    // ---- staging constants: thread = (kg 0..7 -> (kslw,kcw), cw 0..31)
    const int cw   = t & 31;
    const int kg   = (t >> 5) & 7;
    const int kslw = kg >> 2, kcw = kg & 3;
    const int c1u  = cw + 32;                        // unclamped col 32..63
    const int c1   = (c1u < WIN) ? c1u : (WIN - 1);  // value-clamped
    int voff[16];
    #pragma unroll
    for (int j = 0; j < 8; ++j) {
        voff[j]     = (kg * 8 + j) * HW + cw;
        voff[8 + j] = (kg * 8 + j) * HW + c1;
    }
    // write slots: fragment (kslw, kcw, col); slot uses UNCLAMPED col
    const int ws0 = (kslw * 4 + (cw  >> 4)) * 64 + kcw * 16 + (cw  & 15);
    const int ws1 = (kslw * 4 + (c1u >> 4)) * 64 + kcw * 16 + (c1u & 15);
    unsigned short* Wp[2][2];
    Wp[0][0] = &Xs[0][ws0 * 8];  Wp[0][1] = &Xs[0][ws1 * 8];
    Wp[1][0] = &Xs[1][ws0 * 8];  Wp[1][1] = &Xs[1][ws1 * 8];

    const float* xb = x + (size_t)b * (INC * HW);
    const frag8* Afw = (const frag8*)Asw + l;    // + q*2048 + wv*512 + ot*128 + ksl*64
    const frag8* Xf[2] = { (const frag8*)&Xs[0][0] + l,
                           (const frag8*)&Xs[1][0] + l };

    f32x4 acc[4][4];
    #pragma unroll
    for (int ot = 0; ot < 4; ++ot)
        #pragma unroll
        for (int wt = 0; wt < 4; ++wt)
            acc[ot][wt] = (f32x4){0.f, 0.f, 0.f, 0.f};

    frag8 A[4][2];
    float Lv[16];

    // 16 coalesced dword loads for chunk q (always issued; zmask kills pad row)
    auto LOADL = [&](int q) {
        const int kh  = q >> 2, cq = q & 3;
        const int row = 3 * h - 1 + kh;
        const int rc  = row < 0 ? 0 : row;
        const float zmask = row < 0 ? 0.f : 1.f;
        const float* xq = xb + (size_t)cq * 64 * HW + (size_t)rc * WIN;
        #pragma unroll
        for (int i = 0; i < 16; ++i) Lv[i] = xq[voff[i]] * zmask;
    };

    auto LOADA = [&](int q) {
        #pragma unroll
        for (int ot = 0; ot < 4; ++ot)
            #pragma unroll
            for (int ksl = 0; ksl < 2; ++ksl)
                A[ot][ksl] = Afw[q * 2048 + wv * 512 + ot * 128 + ksl * 64];
    };

    // cvt Lv -> 2 bf16 fragments, write to buf q&1
    auto W = [&](int q) {
        const int bp = q & 1;
        union { frag8 fr; unsigned u[4]; } P;
        P.u[0] = cvtpk(Lv[0], Lv[1]);
        P.u[1] = cvtpk(Lv[2], Lv[3]);
        P.u[2] = cvtpk(Lv[4], Lv[5]);
        P.u[3] = cvtpk(Lv[6], Lv[7]);
        *(frag8*)Wp[bp][0] = P.fr;
        P.u[0] = cvtpk(Lv[8],  Lv[9]);
        P.u[1] = cvtpk(Lv[10], Lv[11]);
        P.u[2] = cvtpk(Lv[12], Lv[13]);
        P.u[3] = cvtpk(Lv[14], Lv[15]);
        *(frag8*)Wp[bp][1] = P.fr;
    };

    // ---- prologue: A(0), L(0) -> drain -> W(0); L(1) in flight over barrier
    LOADA(0);
    SB0();
    LOADL(0);
    SB0();
    VMCNT(0);
    W(0);
    LOADL(1);
    SB0();
    LGKM0();
    __builtin_amdgcn_s_barrier();
    FENCE();

    #pragma unroll
    for (int q = 0; q < 12; ++q) {
        // ---- compute(q): 8 ds_read_b128 + 32 MFMA on buf q&1
        const int bp = q & 1;
        #pragma unroll
        for (int ksl = 0; ksl < 2; ++ksl) {
            #pragma unroll
            for (int wt = 0; wt < 4; ++wt) {
                frag8 B = Xf[bp][(ksl * 4 + wt) * 64];
                #pragma unroll
                for (int ot = 0; ot < 4; ++ot)
                    acc[ot][wt] = __builtin_amdgcn_mfma_f32_16x16x32_bf16(
                        A[ot][ksl], B, acc[ot][wt], 0, 0, 0);
            }
        }

        if (q < 11) {
            SB0();                       // compute(q) done before A-reg reuse
            LOADA(q + 1);                // FIFO: newer than L(q+1)
            SB0();
            VMCNT(8);                    // retire L(q+1); keep A(q+1)
            W(q + 1);                    // cvt + 2x ds_write_b128
            if (q < 10) LOADL(q + 2);    // reuse L regs (WAR via cvt uses)
            SB0();
            LGKM0();                     // ds_writes visible before barrier
            __builtin_amdgcn_s_barrier();
            FENCE();
        }
    }

    // ---- store: out col = n+1 for n=0..55; cols 0 and 57 are exact zeros
    #pragma unroll
    for (int ot = 0; ot < 4; ++ot) {
        #pragma unroll
        for (int r = 0; r < 4; ++r) {
            int o = wv * 64 + ot * 16 + hi * 4 + r;
            float* orow = out + ((size_t)(b * 256 + o) * HOUT + h) * WOUT;
            #pragma unroll
            for (int wt = 0; wt < 4; ++wt) {
                int n = wt * 16 + lo;
                if (n < 56) orow[n + 1] = acc[ot][wt][r];
            }
            if (lo == 0) orow[0]  = 0.f;
            if (lo == 1) orow[57] = 0.f;
        }
    }
}

extern "C" void kernel_launch(void* const* d_in, const int* in_sizes, int n_in,
                              void* d_out, int out_size, void* d_ws, size_t ws_size,
                              hipStream_t stream) {
    const float* x     = (const float*)d_in[0];   // (32,256,56,56)
    const float* lego  = (const float*)d_in[1];   // (64,64,3,1)
    const float* coefs = (const float*)d_in[2];   // (4,256,64,1,1)
    const float* comb  = (const float*)d_in[3];   // (4,256,64,1,1)
    float* out = (float*)d_out;                   // (32,256,19,58)

    unsigned short* Asw = (unsigned short*)d_ws;  // 196,608 bf16 = 384 KB

    prep_weff<<<dim3(3, 256), 256, 0, stream>>>(lego, coefs, comb, Asw);
    conv_mfma<<<dim3(HOUT, 32), 256, 0, stream>>>(x, Asw, out);
}